// Round 4
// baseline (192.794 us; speedup 1.0000x reference)
//
#include <hip/hip_runtime.h>
#include <hip/hip_bf16.h>
#include <hip/hip_cooperative_groups.h>
#include <cstdint>
#include <cstddef>

namespace cg = cooperative_groups;

#define N_TOK 4096
#define CQ    256
#define CK    32
// softmax runs in log2 domain: fold 0.125 * log2(e) into Aqk / bqk
#define QK_SCALE 0.18033688011112042f

typedef __attribute__((ext_vector_type(4))) float  f32x4;
typedef __attribute__((ext_vector_type(8))) __bf16 bf16x8;
typedef __attribute__((ext_vector_type(4))) short  s16x4;

__device__ __forceinline__ unsigned short f2bf(float f) {
  union { float f; unsigned u; } x; x.f = f;
  unsigned r = x.u + 0x7FFFu + ((x.u >> 16) & 1u);   // RNE
  return (unsigned short)(r >> 16);
}

__device__ __forceinline__ f32x4 mfma16(bf16x8 a, bf16x8 b, f32x4 c) {
  return __builtin_amdgcn_mfma_f32_16x16x32_bf16(a, b, c, 0, 0, 0);
}

__device__ __forceinline__ float exp2fast(float x) {
#if __has_builtin(__builtin_amdgcn_exp2f)
  return __builtin_amdgcn_exp2f(x);
#else
  float r; asm("v_exp_f32 %0, %1" : "=v"(r) : "v"(x)); return r;
#endif
}

// slot permutation (r8-verified): pos = g*8+j  <->  key_local in 32-key chunk
__device__ __forceinline__ int pos2key(int pos) {
  return ((pos >> 3) << 2) + (pos & 3) + (((pos >> 2) & 1) << 4);
}

// ---------------------------------------------------------------------------
// Prep body: weight folds + xk bf16 prep. Active for blk < 128. (verified)
// ---------------------------------------------------------------------------
__device__ __forceinline__ void prep_body(
    int blk, int t,
    const float* __restrict__ Wq, const float* __restrict__ bq,
    const float* __restrict__ Wk, const float* __restrict__ Wv,
    const float* __restrict__ bv, const float* __restrict__ Wo,
    const float* __restrict__ bo, const float* __restrict__ Fk,
    unsigned short* __restrict__ Aqkt, float* __restrict__ bqk,
    unsigned short* __restrict__ W2bf, float* __restrict__ c2,
    unsigned short* __restrict__ Vpv, unsigned short* __restrict__ XkT)
{
  __shared__ float red[256];
  __shared__ unsigned short trs[128][33];
  if (blk < 32) {
    const int j = blk;
    float acc = 0.f;
    #pragma unroll 16
    for (int i = 0; i < CQ; i++)
      acc = fmaf(Wq[(size_t)i * CQ + t], Wk[(size_t)i * CK + j], acc);
    Aqkt[(size_t)j * CQ + t] = f2bf(QK_SCALE * acc);
    red[t] = bq[t] * Wk[(size_t)t * CK + j];
    __syncthreads();
    for (int s = 128; s > 0; s >>= 1) {
      if (t < s) red[t] += red[t + s];
      __syncthreads();
    }
    if (t == 0) bqk[j] = QK_SCALE * red[0];
  } else if (blk < 64) {
    const int j = blk - 32;
    float acc = 0.f, acc2 = 0.f;
    #pragma unroll 16
    for (int i = 0; i < CQ; i++) {
      float wo = Wo[(size_t)t * CQ + i];
      acc  = fmaf(wo, Wv[(size_t)i * CK + j], acc);
      acc2 = fmaf(wo, bv[i], acc2);
    }
    W2bf[(size_t)t * CK + j] = f2bf(acc);
    if (j == 0) c2[t] = bo[t] + acc2;
  } else if (blk < 128) {
    const int blk2 = blk - 64;
    const int b = blk2 >> 5;
    const int t0 = (blk2 & 31) << 7;
    #pragma unroll
    for (int i = 0; i < 4; i++) {
      int flat = (i * 256 + t) << 2;            // over [32 ch][128 tok]
      int r = flat >> 7, c4 = flat & 127;
      float4 v = *(const float4*)(Fk + ((size_t)(b * CK + r)) * N_TOK + t0 + c4);
      ushort4 u = { f2bf(v.x), f2bf(v.y), f2bf(v.z), f2bf(v.w) };
      trs[c4][r] = u.x; trs[c4+1][r] = u.y; trs[c4+2][r] = u.z; trs[c4+3][r] = u.w;
    }
    __syncthreads();
    {   // XkT: token-major (coalesced 32B/thread)
      const int token = t >> 1, half = t & 1;
      unsigned short tmp[16] __attribute__((aligned(16)));
      #pragma unroll
      for (int k = 0; k < 16; k++) tmp[k] = trs[token][half * 16 + k];
      unsigned short* dst = XkT + ((size_t)(b * N_TOK + t0 + token)) * CK + half * 16;
      ((uint4*)dst)[0] = ((const uint4*)tmp)[0];
      ((uint4*)dst)[1] = ((const uint4*)tmp)[1];
    }
    {   // Vpv[chunk32][d][pos]: thread = (chunk-local(4), d(32), pos-half(2))
      const int ch32l = t >> 6, d = (t & 63) >> 1, ph = t & 1;
      unsigned short tmp[16] __attribute__((aligned(16)));
      #pragma unroll
      for (int i = 0; i < 16; i++) {
        int pos = ph * 16 + i;
        tmp[i] = trs[ch32l * 32 + pos2key(pos)][d];
      }
      unsigned short* dst = Vpv +
          (((size_t)(b * 128 + (t0 >> 5) + ch32l)) * 32 + d) * 32 + ph * 16;
      ((uint4*)dst)[0] = ((const uint4*)tmp)[0];
      ((uint4*)dst)[1] = ((const uint4*)tmp)[1];
    }
  }
}

// ---------------------------------------------------------------------------
// Fused body: qproj (distributed across waves) + flash + merge + oproj +
// residual. blk in [0,512): b = blk>>8, 16-token tile t0 = (blk&255)*16.
// Wave w: key-quarter [w*1024, w*1024+1024), 4 chunks of 256, barrier-free
// flash loop (K/V direct from L2-resident XkT/Vpv; verified r7/r8 pipeline).
// ---------------------------------------------------------------------------
__device__ __forceinline__ void fused_body(
    int blk, int t,
    const float* __restrict__ X, const unsigned short* __restrict__ Aqkt,
    const float* __restrict__ bqk, const unsigned short* __restrict__ XkT,
    const unsigned short* __restrict__ Vpv,
    const unsigned short* __restrict__ W2bf, const float* __restrict__ c2,
    float* __restrict__ Y)
{
  __shared__ unsigned short qn[16][40] __attribute__((aligned(16)));
  __shared__ float qp[4][16][33];
  __shared__ float ml[4][2][16];
  __shared__ float ow[4][16][34];

  const int b  = blk >> 8;
  const int t0 = (blk & 255) << 4;
  const int w = t >> 6;
  const int lane = t & 63, c = lane & 15, g = lane >> 4;

  // ---- qproj: wave w handles kk = 2w, 2w+1 (K-split), partials via LDS ----
  f32x4 qacc[2] = {};
  #pragma unroll
  for (int ki = 0; ki < 2; ki++) {
    const int kk = w * 2 + ki;
    const float* xb = X + ((size_t)(b * CQ + kk * 32 + g * 8)) * N_TOK + t0 + c;
    union { unsigned short u[8]; bf16x8 v; } a;
    #pragma unroll
    for (int j = 0; j < 8; j++) a.u[j] = f2bf(xb[(size_t)j * N_TOK]);
    #pragma unroll
    for (int nt = 0; nt < 2; nt++) {
      bf16x8 bB = *(const bf16x8*)(Aqkt + (size_t)(nt * 16 + c) * CQ + kk * 32 + g * 8);
      qacc[nt] = mfma16(a.v, bB, qacc[nt]);
    }
  }
  #pragma unroll
  for (int nt = 0; nt < 2; nt++)
    #pragma unroll
    for (int r = 0; r < 4; r++)
      qp[w][g * 4 + r][nt * 16 + c] = qacc[nt][r];   // row=token, col=dim
  __syncthreads();
  {
    const int tok = t >> 4, d2 = (t & 15) * 2;
    #pragma unroll
    for (int dd = 0; dd < 2; dd++) {
      const int d = d2 + dd;
      float sv = ((qp[0][tok][d] + qp[1][tok][d]) +
                  (qp[2][tok][d] + qp[3][tok][d])) + bqk[d];
      qn[tok][d] = f2bf(sv);
    }
  }
  __syncthreads();
  const bf16x8 qf = *(const bf16x8*)&qn[c][g * 8];

  // ---- flash: wave's 1024 keys, 4 chunks of 256, barrier-free ----
  const unsigned short* kb = XkT + ((size_t)(b * N_TOK + w * 1024)) * CK;
  const unsigned short* vp = Vpv + (size_t)b * 128 * 1024;   // [ch32][32d][32pos]
  float mO = -1e30f, lO = 0.f;
  f32x4 O0 = {}, O1 = {};

  for (int chb = 0; chb < 4; chb++) {
    // ---- phase 1: S^T for 256 keys (K direct from L2) ----
    f32x4 sc[4][4];
    #pragma unroll
    for (int it = 0; it < 4; it++)
      #pragma unroll
      for (int nt = 0; nt < 4; nt++) {
        bf16x8 ak = *(const bf16x8*)(kb +
            (size_t)(chb * 256 + it * 64 + nt * 16 + c) * CK + g * 8);
        f32x4 z = {};
        sc[it][nt] = mfma16(ak, qf, z);    // row=key(g*4+r), col=token(c)
      }

    // ---- phase 2: per-token max (log2 domain) ----
    float mx = -1e30f;
    #pragma unroll
    for (int it = 0; it < 4; it++)
      #pragma unroll
      for (int nt = 0; nt < 4; nt++)
        mx = fmaxf(mx, fmaxf(fmaxf(sc[it][nt][0], sc[it][nt][1]),
                             fmaxf(sc[it][nt][2], sc[it][nt][3])));
    mx = fmaxf(mx, __shfl_xor(mx, 16));
    mx = fmaxf(mx, __shfl_xor(mx, 32));

    // ---- phase 3: exp2, sum, pack P^T (register-resident) ----
    float l = 0.f;
    s16x4 pf[4][4];
    #pragma unroll
    for (int it = 0; it < 4; it++)
      #pragma unroll
      for (int nt = 0; nt < 4; nt++) {
        float p0 = exp2fast(sc[it][nt][0] - mx);
        float p1 = exp2fast(sc[it][nt][1] - mx);
        float p2 = exp2fast(sc[it][nt][2] - mx);
        float p3 = exp2fast(sc[it][nt][3] - mx);
        l += (p0 + p1) + (p2 + p3);
        union { __hip_bfloat162 h2[2]; s16x4 v; } pu;
        pu.h2[0] = __float22bfloat162_rn(make_float2(p0, p1));
        pu.h2[1] = __float22bfloat162_rn(make_float2(p2, p3));
        pf[it][nt] = pu.v;
      }
    l += __shfl_xor(l, 16);
    l += __shfl_xor(l, 32);

    // ---- phase 4: O^T = V^T P^T (V direct from L2, verified pattern) ----
    f32x4 o0 = {}, o1 = {};
    #pragma unroll
    for (int it = 0; it < 4; it++)
      #pragma unroll
      for (int ntp = 0; ntp < 2; ntp++) {
        const int ch32 = w * 32 + chb * 8 + it * 2 + ntp;
        const unsigned short* base = vp + (size_t)ch32 * 1024;
        union { s16x4 h[2]; bf16x8 v; } bu;
        bu.h[0] = pf[it][ntp * 2];
        bu.h[1] = pf[it][ntp * 2 + 1];
        bf16x8 a0 = *(const bf16x8*)(base + c * 32 + g * 8);          // d=c
        bf16x8 a1 = *(const bf16x8*)(base + (16 + c) * 32 + g * 8);   // d=16+c
        o0 = mfma16(a0, bu.v, o0);         // row=d(g*4+r), col=token(c)
        o1 = mfma16(a1, bu.v, o1);
      }

    // ---- running register merge (log2 domain) ----
    float mN = fmaxf(mO, mx);
    float fO = exp2fast(mO - mN), fP = exp2fast(mx - mN);
    lO = lO * fO + l * fP;
    #pragma unroll
    for (int r = 0; r < 4; r++) {
      O0[r] = O0[r] * fO + o0[r] * fP;
      O1[r] = O1[r] * fO + o1[r] * fP;
    }
    mO = mN;
  }

  // ---- 4-way cross-wave merge via LDS ----
  if (lane < 16) { ml[w][0][c] = mO; ml[w][1][c] = lO; }
  #pragma unroll
  for (int r = 0; r < 4; r++) {
    ow[w][c][g * 4 + r]      = O0[r];
    ow[w][c][16 + g * 4 + r] = O1[r];
  }
  __syncthreads();

  float m4[4], l4[4], mM = -1e30f;
  #pragma unroll
  for (int k = 0; k < 4; k++) {
    m4[k] = ml[k][0][c]; l4[k] = ml[k][1][c];
    mM = fmaxf(mM, m4[k]);
  }
  float f4[4], ls = 0.f;
  #pragma unroll
  for (int k = 0; k < 4; k++) {
    f4[k] = exp2fast(m4[k] - mM);
    ls = fmaf(f4[k], l4[k], ls);
  }
  const float inv = 1.0f / ls;
  union { unsigned short u[8]; bf16x8 v; } wb;
  #pragma unroll
  for (int j = 0; j < 8; j++) {
    float acc = 0.f;
    #pragma unroll
    for (int k = 0; k < 4; k++)
      acc = fmaf(f4[k], ow[k][c][g * 8 + j], acc);
    wb.u[j] = f2bf(acc * inv);             // ON[tok c][dim g*8+j]
  }

  // ---- fused output projection + residual (verified oproj phase B) ----
  const int m0 = w * 64;
  f32x4 acc2[4] = {};
  #pragma unroll
  for (int mt = 0; mt < 4; mt++) {
    bf16x8 aW = *(const bf16x8*)(W2bf + (size_t)(m0 + mt * 16 + c) * CK + g * 8);
    acc2[mt] = mfma16(aW, wb.v, acc2[mt]);
  }
  #pragma unroll
  for (int mt = 0; mt < 4; mt++)
    #pragma unroll
    for (int r = 0; r < 4; r++) {
      const int row = m0 + mt * 16 + g * 4 + r;
      size_t idx = ((size_t)(b * CQ + row)) * N_TOK + t0 + c;
      Y[idx] = acc2[mt][r] + c2[row] + X[idx];
    }
}

// ---------------------------------------------------------------------------
// Mono: cooperative single-launch (prep -> grid.sync -> fused). Grid 512 x
// 256, 2 blocks/CU co-resident (LDS ~28 KB, launch_bounds caps VGPR).
// ---------------------------------------------------------------------------
__global__ __launch_bounds__(256, 2) void mono_kernel(
    const float* __restrict__ X, const float* __restrict__ Fk,
    const float* __restrict__ Wq, const float* __restrict__ bq,
    const float* __restrict__ Wk, const float* __restrict__ Wv,
    const float* __restrict__ bv, const float* __restrict__ Wo,
    const float* __restrict__ bo,
    unsigned short* __restrict__ XkT, unsigned short* __restrict__ Vpv,
    unsigned short* __restrict__ Aqkt, unsigned short* __restrict__ W2bf,
    float* __restrict__ bqk, float* __restrict__ c2,
    float* __restrict__ Y)
{
  prep_body(blockIdx.x, threadIdx.x, Wq, bq, Wk, Wv, bv, Wo, bo, Fk,
            Aqkt, bqk, W2bf, c2, Vpv, XkT);
  cg::this_grid().sync();
  fused_body(blockIdx.x, threadIdx.x, X, Aqkt, bqk, XkT, Vpv, W2bf, c2, Y);
}

// ---- fallback two-launch path (verified round-3 structure) ----
__global__ __launch_bounds__(256) void prep_kernel(
    const float* __restrict__ Wq, const float* __restrict__ bq,
    const float* __restrict__ Wk, const float* __restrict__ Wv,
    const float* __restrict__ bv, const float* __restrict__ Wo,
    const float* __restrict__ bo, const float* __restrict__ Fk,
    unsigned short* __restrict__ Aqkt, float* __restrict__ bqk,
    unsigned short* __restrict__ W2bf, float* __restrict__ c2,
    unsigned short* __restrict__ Vpv, unsigned short* __restrict__ XkT)
{
  prep_body(blockIdx.x, threadIdx.x, Wq, bq, Wk, Wv, bv, Wo, bo, Fk,
            Aqkt, bqk, W2bf, c2, Vpv, XkT);
}

__global__ __launch_bounds__(256, 2) void fused_kernel(
    const float* __restrict__ X, const unsigned short* __restrict__ Aqkt,
    const float* __restrict__ bqk, const unsigned short* __restrict__ XkT,
    const unsigned short* __restrict__ Vpv,
    const unsigned short* __restrict__ W2bf, const float* __restrict__ c2,
    float* __restrict__ Y)
{
  fused_body(blockIdx.x, threadIdx.x, X, Aqkt, bqk, XkT, Vpv, W2bf, c2, Y);
}

// ---------------------------------------------------------------------------
extern "C" void kernel_launch(void* const* d_in, const int* in_sizes, int n_in,
                              void* d_out, int out_size, void* d_ws, size_t ws_size,
                              hipStream_t stream) {
  const float* F  = (const float*)d_in[0];   // [2,256,4096]
  const float* Fk = (const float*)d_in[1];   // [2,32,4096]
  const float* Wq = (const float*)d_in[2];
  const float* bq = (const float*)d_in[3];
  const float* Wk = (const float*)d_in[4];
  // bk (d_in[5]) is provably softmax-invariant -> dropped
  const float* Wv = (const float*)d_in[6];
  const float* bv = (const float*)d_in[7];
  const float* Wo = (const float*)d_in[8];
  const float* bo = (const float*)d_in[9];
  float* Y = (float*)d_out;
  char* ws = (char*)d_ws;
  unsigned short* XkT   = (unsigned short*)(ws);                 // 512 KB [2,4096,32]
  unsigned short* Vpv   = (unsigned short*)(ws + (512u << 10));  // 512 KB [2,128,32,32]
  unsigned short* Aqkt  = (unsigned short*)(ws + (2048u << 10)); // 16 KB  [32,256]
  unsigned short* W2bf  = (unsigned short*)(ws + (2080u << 10)); // 16 KB  [256,32]
  float*          bqk   = (float*)(ws + (2112u << 10));          // 128 B
  float*          c2    = (float*)(ws + (2116u << 10));          // 1 KB

  void* args[16] = {
    (void*)&F, (void*)&Fk, (void*)&Wq, (void*)&bq, (void*)&Wk, (void*)&Wv,
    (void*)&bv, (void*)&Wo, (void*)&bo, (void*)&XkT, (void*)&Vpv,
    (void*)&Aqkt, (void*)&W2bf, (void*)&bqk, (void*)&c2, (void*)&Y
  };
  hipError_t e = hipLaunchCooperativeKernel((const void*)mono_kernel,
                                            dim3(512), dim3(256),
                                            args, 0, stream);
  if (e != hipSuccess) {
    // fallback: verified two-launch pipeline
    prep_kernel <<<128, 256, 0, stream>>>(Wq, bq, Wk, Wv, bv, Wo, bo, Fk,
                                          Aqkt, bqk, W2bf, c2, Vpv, XkT);
    fused_kernel<<<512, 256, 0, stream>>>(F, Aqkt, bqk, XkT, Vpv, W2bf, c2, Y);
  }
}

// Round 6
// 118.025 us; speedup vs baseline: 1.6335x; 1.6335x over previous
//
#include <hip/hip_runtime.h>
#include <hip/hip_bf16.h>
#include <cstdint>
#include <cstddef>

#define N_TOK 4096
#define CQ    256
#define CK    32
// softmax runs in log2 domain: fold 0.125 * log2(e) into Aqk / bqk
#define QK_SCALE 0.18033688011112042f

typedef __attribute__((ext_vector_type(4))) float  f32x4;
typedef __attribute__((ext_vector_type(8))) __bf16 bf16x8;
typedef __attribute__((ext_vector_type(4))) short  s16x4;

__device__ __forceinline__ unsigned short f2bf(float f) {
  union { float f; unsigned u; } x; x.f = f;
  unsigned r = x.u + 0x7FFFu + ((x.u >> 16) & 1u);   // RNE
  return (unsigned short)(r >> 16);
}

__device__ __forceinline__ f32x4 mfma16(bf16x8 a, bf16x8 b, f32x4 c) {
  return __builtin_amdgcn_mfma_f32_16x16x32_bf16(a, b, c, 0, 0, 0);
}

__device__ __forceinline__ float exp2fast(float x) {
#if __has_builtin(__builtin_amdgcn_exp2f)
  return __builtin_amdgcn_exp2f(x);
#else
  float r; asm("v_exp_f32 %0, %1" : "=v"(r) : "v"(x)); return r;
#endif
}

// slot permutation (r8-verified): pos = g*8+j  <->  key_local in 32-key chunk
__device__ __forceinline__ int pos2key(int pos) {
  return ((pos >> 3) << 2) + (pos & 3) + (((pos >> 2) & 1) << 4);
}

// ---------------------------------------------------------------------------
// Prep: weight folds + xk bf16 prep. Grid 128 x 256. (unchanged, verified)
// ---------------------------------------------------------------------------
__global__ __launch_bounds__(256) void prep_kernel(
    const float* __restrict__ Wq, const float* __restrict__ bq,
    const float* __restrict__ Wk, const float* __restrict__ Wv,
    const float* __restrict__ bv, const float* __restrict__ Wo,
    const float* __restrict__ bo, const float* __restrict__ Fk,
    unsigned short* __restrict__ Aqkt, float* __restrict__ bqk,
    unsigned short* __restrict__ W2bf, float* __restrict__ c2,
    unsigned short* __restrict__ Vpv, unsigned short* __restrict__ XkT)
{
  __shared__ float red[256];
  __shared__ unsigned short trs[128][33];
  const int blk = blockIdx.x, t = threadIdx.x;
  if (blk < 32) {
    const int j = blk;
    float acc = 0.f;
    #pragma unroll 16
    for (int i = 0; i < CQ; i++)
      acc = fmaf(Wq[(size_t)i * CQ + t], Wk[(size_t)i * CK + j], acc);
    Aqkt[(size_t)j * CQ + t] = f2bf(QK_SCALE * acc);
    red[t] = bq[t] * Wk[(size_t)t * CK + j];
    __syncthreads();
    for (int s = 128; s > 0; s >>= 1) {
      if (t < s) red[t] += red[t + s];
      __syncthreads();
    }
    if (t == 0) bqk[j] = QK_SCALE * red[0];
  } else if (blk < 64) {
    const int j = blk - 32;
    float acc = 0.f, acc2 = 0.f;
    #pragma unroll 16
    for (int i = 0; i < CQ; i++) {
      float wo = Wo[(size_t)t * CQ + i];
      acc  = fmaf(wo, Wv[(size_t)i * CK + j], acc);
      acc2 = fmaf(wo, bv[i], acc2);
    }
    W2bf[(size_t)t * CK + j] = f2bf(acc);
    if (j == 0) c2[t] = bo[t] + acc2;
  } else {
    const int blk2 = blk - 64;
    const int b = blk2 >> 5;
    const int t0 = (blk2 & 31) << 7;
    #pragma unroll
    for (int i = 0; i < 4; i++) {
      int flat = (i * 256 + t) << 2;            // over [32 ch][128 tok]
      int r = flat >> 7, c4 = flat & 127;
      float4 v = *(const float4*)(Fk + ((size_t)(b * CK + r)) * N_TOK + t0 + c4);
      ushort4 u = { f2bf(v.x), f2bf(v.y), f2bf(v.z), f2bf(v.w) };
      trs[c4][r] = u.x; trs[c4+1][r] = u.y; trs[c4+2][r] = u.z; trs[c4+3][r] = u.w;
    }
    __syncthreads();
    {   // XkT: token-major (coalesced 32B/thread)
      const int token = t >> 1, half = t & 1;
      unsigned short tmp[16] __attribute__((aligned(16)));
      #pragma unroll
      for (int k = 0; k < 16; k++) tmp[k] = trs[token][half * 16 + k];
      unsigned short* dst = XkT + ((size_t)(b * N_TOK + t0 + token)) * CK + half * 16;
      ((uint4*)dst)[0] = ((const uint4*)tmp)[0];
      ((uint4*)dst)[1] = ((const uint4*)tmp)[1];
    }
    {   // Vpv[chunk32][d][pos]: thread = (chunk-local(4), d(32), pos-half(2))
      const int ch32l = t >> 6, d = (t & 63) >> 1, ph = t & 1;
      unsigned short tmp[16] __attribute__((aligned(16)));
      #pragma unroll
      for (int i = 0; i < 16; i++) {
        int pos = ph * 16 + i;
        tmp[i] = trs[ch32l * 32 + pos2key(pos)][d];
      }
      unsigned short* dst = Vpv +
          (((size_t)(b * 128 + (t0 >> 5) + ch32l)) * 32 + d) * 32 + ph * 16;
      ((uint4*)dst)[0] = ((const uint4*)tmp)[0];
      ((uint4*)dst)[1] = ((const uint4*)tmp)[1];
    }
  }
}

// ---------------------------------------------------------------------------
// Fused qproj + flash + merge + oproj + residual, v3.
// Round-3 verified structure (grid 512 = 2 blocks/CU, barrier-free flash
// loop, K/V direct from L2) + round-4-verified DISTRIBUTED qproj: wave w
// computes kk = {2w, 2w+1} K-blocks only; 4 f32 partials reduced via LDS.
// 3 __syncthreads total; LDS ~19 KB.
// ---------------------------------------------------------------------------
__global__ __launch_bounds__(256, 2) void fused_kernel(
    const float* __restrict__ X, const unsigned short* __restrict__ Aqkt,
    const float* __restrict__ bqk, const unsigned short* __restrict__ XkT,
    const unsigned short* __restrict__ Vpv,
    const unsigned short* __restrict__ W2bf, const float* __restrict__ c2,
    float* __restrict__ Y)
{
  __shared__ unsigned short qn[16][40] __attribute__((aligned(16)));
  __shared__ float qp[4][16][33];
  __shared__ float ml[4][2][16];
  __shared__ float ow[4][16][34];

  const int b  = blockIdx.x >> 8;
  const int t0 = (blockIdx.x & 255) << 4;
  const int t = threadIdx.x, w = t >> 6;
  const int lane = t & 63, c = lane & 15, g = lane >> 4;

  // ---- qproj: wave w handles kk = 2w, 2w+1 (K-split), partials via LDS ----
  f32x4 qacc[2] = {};
  #pragma unroll
  for (int ki = 0; ki < 2; ki++) {
    const int kk = w * 2 + ki;
    const float* xb = X + ((size_t)(b * CQ + kk * 32 + g * 8)) * N_TOK + t0 + c;
    union { unsigned short u[8]; bf16x8 v; } a;
    #pragma unroll
    for (int j = 0; j < 8; j++) a.u[j] = f2bf(xb[(size_t)j * N_TOK]);
    #pragma unroll
    for (int nt = 0; nt < 2; nt++) {
      bf16x8 bB = *(const bf16x8*)(Aqkt + (size_t)(nt * 16 + c) * CQ + kk * 32 + g * 8);
      qacc[nt] = mfma16(a.v, bB, qacc[nt]);
    }
  }
  #pragma unroll
  for (int nt = 0; nt < 2; nt++)
    #pragma unroll
    for (int r = 0; r < 4; r++)
      qp[w][g * 4 + r][nt * 16 + c] = qacc[nt][r];   // row=token, col=dim
  __syncthreads();
  {
    const int tok = t >> 4, d2 = (t & 15) * 2;
    #pragma unroll
    for (int dd = 0; dd < 2; dd++) {
      const int d = d2 + dd;
      float sv = ((qp[0][tok][d] + qp[1][tok][d]) +
                  (qp[2][tok][d] + qp[3][tok][d])) + bqk[d];
      qn[tok][d] = f2bf(sv);
    }
  }
  __syncthreads();
  const bf16x8 qf = *(const bf16x8*)&qn[c][g * 8];

  // ---- flash: wave's 1024 keys, 4 chunks of 256, barrier-free ----
  const unsigned short* kb = XkT + ((size_t)(b * N_TOK + w * 1024)) * CK;
  const unsigned short* vp = Vpv + (size_t)b * 128 * 1024;   // [ch32][32d][32pos]
  float mO = -1e30f, lO = 0.f;
  f32x4 O0 = {}, O1 = {};

  for (int chb = 0; chb < 4; chb++) {
    // ---- phase 1: S^T for 256 keys (K direct from L2) ----
    f32x4 sc[4][4];
    #pragma unroll
    for (int it = 0; it < 4; it++)
      #pragma unroll
      for (int nt = 0; nt < 4; nt++) {
        bf16x8 ak = *(const bf16x8*)(kb +
            (size_t)(chb * 256 + it * 64 + nt * 16 + c) * CK + g * 8);
        f32x4 z = {};
        sc[it][nt] = mfma16(ak, qf, z);    // row=key(g*4+r), col=token(c)
      }

    // ---- phase 2: per-token max (log2 domain) ----
    float mx = -1e30f;
    #pragma unroll
    for (int it = 0; it < 4; it++)
      #pragma unroll
      for (int nt = 0; nt < 4; nt++)
        mx = fmaxf(mx, fmaxf(fmaxf(sc[it][nt][0], sc[it][nt][1]),
                             fmaxf(sc[it][nt][2], sc[it][nt][3])));
    mx = fmaxf(mx, __shfl_xor(mx, 16));
    mx = fmaxf(mx, __shfl_xor(mx, 32));

    // ---- phase 3: exp2, sum, pack P^T (register-resident) ----
    float l = 0.f;
    s16x4 pf[4][4];
    #pragma unroll
    for (int it = 0; it < 4; it++)
      #pragma unroll
      for (int nt = 0; nt < 4; nt++) {
        float p0 = exp2fast(sc[it][nt][0] - mx);
        float p1 = exp2fast(sc[it][nt][1] - mx);
        float p2 = exp2fast(sc[it][nt][2] - mx);
        float p3 = exp2fast(sc[it][nt][3] - mx);
        l += (p0 + p1) + (p2 + p3);
        union { __hip_bfloat162 h2[2]; s16x4 v; } pu;
        pu.h2[0] = __float22bfloat162_rn(make_float2(p0, p1));
        pu.h2[1] = __float22bfloat162_rn(make_float2(p2, p3));
        pf[it][nt] = pu.v;
      }
    l += __shfl_xor(l, 16);
    l += __shfl_xor(l, 32);

    // ---- phase 4: O^T = V^T P^T (V direct from L2, verified pattern) ----
    f32x4 o0 = {}, o1 = {};
    #pragma unroll
    for (int it = 0; it < 4; it++)
      #pragma unroll
      for (int ntp = 0; ntp < 2; ntp++) {
        const int ch32 = w * 32 + chb * 8 + it * 2 + ntp;
        const unsigned short* base = vp + (size_t)ch32 * 1024;
        union { s16x4 h[2]; bf16x8 v; } bu;
        bu.h[0] = pf[it][ntp * 2];
        bu.h[1] = pf[it][ntp * 2 + 1];
        bf16x8 a0 = *(const bf16x8*)(base + c * 32 + g * 8);          // d=c
        bf16x8 a1 = *(const bf16x8*)(base + (16 + c) * 32 + g * 8);   // d=16+c
        o0 = mfma16(a0, bu.v, o0);         // row=d(g*4+r), col=token(c)
        o1 = mfma16(a1, bu.v, o1);
      }

    // ---- running register merge (log2 domain) ----
    float mN = fmaxf(mO, mx);
    float fO = exp2fast(mO - mN), fP = exp2fast(mx - mN);
    lO = lO * fO + l * fP;
    #pragma unroll
    for (int r = 0; r < 4; r++) {
      O0[r] = O0[r] * fO + o0[r] * fP;
      O1[r] = O1[r] * fO + o1[r] * fP;
    }
    mO = mN;
  }

  // ---- 4-way cross-wave merge via LDS ----
  if (lane < 16) { ml[w][0][c] = mO; ml[w][1][c] = lO; }
  #pragma unroll
  for (int r = 0; r < 4; r++) {
    ow[w][c][g * 4 + r]      = O0[r];
    ow[w][c][16 + g * 4 + r] = O1[r];
  }
  __syncthreads();

  float m4[4], l4[4], mM = -1e30f;
  #pragma unroll
  for (int k = 0; k < 4; k++) {
    m4[k] = ml[k][0][c]; l4[k] = ml[k][1][c];
    mM = fmaxf(mM, m4[k]);
  }
  float f4[4], ls = 0.f;
  #pragma unroll
  for (int k = 0; k < 4; k++) {
    f4[k] = exp2fast(m4[k] - mM);
    ls = fmaf(f4[k], l4[k], ls);
  }
  const float inv = 1.0f / ls;
  union { unsigned short u[8]; bf16x8 v; } wb;
  #pragma unroll
  for (int j = 0; j < 8; j++) {
    float acc = 0.f;
    #pragma unroll
    for (int k = 0; k < 4; k++)
      acc = fmaf(f4[k], ow[k][c][g * 8 + j], acc);
    wb.u[j] = f2bf(acc * inv);             // ON[tok c][dim g*8+j]
  }

  // ---- fused output projection + residual (verified oproj phase B) ----
  const int m0 = w * 64;
  f32x4 acc2[4] = {};
  #pragma unroll
  for (int mt = 0; mt < 4; mt++) {
    bf16x8 aW = *(const bf16x8*)(W2bf + (size_t)(m0 + mt * 16 + c) * CK + g * 8);
    acc2[mt] = mfma16(aW, wb.v, acc2[mt]);
  }
  #pragma unroll
  for (int mt = 0; mt < 4; mt++)
    #pragma unroll
    for (int r = 0; r < 4; r++) {
      const int row = m0 + mt * 16 + g * 4 + r;
      size_t idx = ((size_t)(b * CQ + row)) * N_TOK + t0 + c;
      Y[idx] = acc2[mt][r] + c2[row] + X[idx];
    }
}

// ---------------------------------------------------------------------------
extern "C" void kernel_launch(void* const* d_in, const int* in_sizes, int n_in,
                              void* d_out, int out_size, void* d_ws, size_t ws_size,
                              hipStream_t stream) {
  const float* F  = (const float*)d_in[0];   // [2,256,4096]
  const float* Fk = (const float*)d_in[1];   // [2,32,4096]
  const float* Wq = (const float*)d_in[2];
  const float* bq = (const float*)d_in[3];
  const float* Wk = (const float*)d_in[4];
  // bk (d_in[5]) is provably softmax-invariant -> dropped
  const float* Wv = (const float*)d_in[6];
  const float* bv = (const float*)d_in[7];
  const float* Wo = (const float*)d_in[8];
  const float* bo = (const float*)d_in[9];
  float* Y = (float*)d_out;
  char* ws = (char*)d_ws;
  unsigned short* XkT   = (unsigned short*)(ws);                 // 512 KB [2,4096,32]
  unsigned short* Vpv   = (unsigned short*)(ws + (512u << 10));  // 512 KB [2,128,32,32]
  unsigned short* Aqkt  = (unsigned short*)(ws + (2048u << 10)); // 16 KB  [32,256]
  unsigned short* W2bf  = (unsigned short*)(ws + (2080u << 10)); // 16 KB  [256,32]
  float*          bqk   = (float*)(ws + (2112u << 10));          // 128 B
  float*          c2    = (float*)(ws + (2116u << 10));          // 1 KB

  prep_kernel <<<128, 256, 0, stream>>>(Wq, bq, Wk, Wv, bv, Wo, bo, Fk,
                                        Aqkt, bqk, W2bf, c2, Vpv, XkT);
  fused_kernel<<<512, 256, 0, stream>>>(F, Aqkt, bqk, XkT, Vpv, W2bf, c2, Y);
}